// Round 7
// baseline (316.963 us; speedup 1.0000x reference)
//
#include <hip/hip_runtime.h>
#include <hip/hip_bf16.h>

typedef unsigned short u16;
typedef unsigned int   u32;
typedef unsigned long long u64;

#define BATCH 4096
#define IDIM  1024
#define ODIM  1024
#define NDEG  9                 // degree 8 -> 9 basis terms
#define KTOT  (IDIM * NDEG)     // 9216

typedef __attribute__((ext_vector_type(8))) short short8_t;   // 8 bf16 = 4 VGPRs
typedef __attribute__((ext_vector_type(4))) float f32x4;
typedef __attribute__((ext_vector_type(4))) u32   u32x4;

// round-to-nearest-even f32 -> bf16
__device__ __forceinline__ u16 f2bf(float f) {
    union { float f; u32 u; } v; v.f = f;
    u32 r = v.u + 0x7FFFu + ((v.u >> 16) & 1u);
    return (u16)(r >> 16);
}
__device__ __forceinline__ u32 pack2bf(float lo, float hi) {
    return (u32)f2bf(lo) | ((u32)f2bf(hi) << 16);
}

// async 16B global -> LDS (wave-uniform LDS base + lane*16)
__device__ __forceinline__ void gl_lds16(const u16* g, u16* l) {
    __builtin_amdgcn_global_load_lds(
        (const __attribute__((address_space(1))) void*)g,
        (__attribute__((address_space(3))) void*)l,
        16, 0, 0);
}

// ---------------------------------------------------------------------------
// prep: Bt[o][k=d*1024+i] <- coeffs[i][o][d] (LDS transpose), 1024 blocks.
// (A is no longer materialized — basis is generated inside the GEMM.)
// ---------------------------------------------------------------------------
#define PB_TI 128
#define PB_TO 8
#define PB_J  (PB_TO * NDEG)    // 72
#define PB_LS 132               // LDS row stride (u16): 264 B, u64-aligned rows

__global__ void prep_kernel(const float* __restrict__ c, u16* __restrict__ Bt) {
    __shared__ u16 lds[PB_J * PB_LS];             // 19 KB
    const int bb  = blockIdx.x;
    const int tid = threadIdx.x;
    const int i0 = (bb & 7) * PB_TI;
    const int o0 = (bb >> 3) * PB_TO;
    const float* src = c + (size_t)i0 * (ODIM * NDEG) + (size_t)o0 * NDEG;
#pragma unroll
    for (int t = 0; t < 36; ++t) {
        int f  = t * 256 + tid;
        int ii = f / PB_J;
        int j  = f - ii * PB_J;
        float v = src[(size_t)ii * (ODIM * NDEG) + j];
        lds[j * PB_LS + ii] = f2bf(v);
    }
    __syncthreads();
#pragma unroll
    for (int t = 0; t < 9; ++t) {
        int g   = t * 256 + tid;
        int j   = g >> 5;
        int ii4 = (g & 31) << 2;
        int o   = j / NDEG;
        int d   = j - o * NDEG;
        u64 v = *(const u64*)(lds + j * PB_LS + ii4);
        *(u64*)(Bt + (size_t)(o0 + o) * KTOT + d * 1024 + i0 + ii4) = v;
    }
}

// ---------------------------------------------------------------------------
// Fused GEMM: P[z] = V(tanh X) * Bt^T, 128x128 tile, 4 waves of 64x64.
// A-panes are GENERATED in-kernel: K walked as (i-window outer, d inner);
// per i-window each thread holds 32 tanh values + (V_{d-2},V_{d-1}) state,
// producing the 16 KB A-pane via ds_write_b128 while B-tile DMA is in
// flight. Same swizzled pane layout / frag reads / epilogue as R4 (920 TF).
// Split-K=2 balanced at (d=4, i=512): both halves = 72 chunks.
// XCD swizzle: per XCD one 1024-row x 512-col patch at one K-half.
// ---------------------------------------------------------------------------
__global__ __launch_bounds__(256, 2)
void gemm_kernel(const float* __restrict__ X, const u16* __restrict__ B,
                 float* __restrict__ P) {
    __shared__ __align__(16) u16 ldsA[128 * 64];  // 16 KB
    __shared__ __align__(16) u16 ldsB[128 * 64];  // 16 KB

    const int tid  = threadIdx.x;
    const int lane = tid & 63;
    const int wave = tid >> 6;
    const int quad = lane >> 4;
    const int l15  = lane & 15;
    const int wm   = wave & 1;
    const int wn   = wave >> 1;

    const int bid = blockIdx.x;                   // 0..511
    const int xcd = bid & 7;
    const int loc = bid >> 3;                     // 0..63
    const int z   = xcd >> 2;
    const int bm  = ((xcd & 3) << 3) | (loc >> 3);
    const int bn  = loc & 7;

    // B staging: 1024 16B slots, XOR-swizzled chunks (as R4)
    const u16* gb[4]; u16* lb[4];
#pragma unroll
    for (int t = 0; t < 4; ++t) {
        int s  = t * 256 + tid;
        int r  = s >> 3;
        int sc = (s & 7) ^ (r & 7);
        gb[t] = B + (size_t)(bn * 128 + r) * KTOT + sc * 8;
        lb[t] = ldsB + s * 8;
    }

    // pane-gen mapping: thread -> (pane row, half of 64-i window)
    const int pr = tid >> 1;                      // 0..127
    const int ph = tid & 1;                       // i-local base = ph*32
    const float* xrow = X + (size_t)(bm * 128 + pr) * IDIM + ph * 32;

    f32x4 acc[4][4];
#pragma unroll
    for (int mt = 0; mt < 4; ++mt)
#pragma unroll
        for (int nt = 0; nt < 4; ++nt)
            acc[mt][nt] = (f32x4){0.f, 0.f, 0.f, 0.f};

    for (int iw = 0; iw < 16; ++iw) {
        // ---- load x window, tanh once ----
        float tv[32];
        const f32x4* xp = (const f32x4*)(xrow + iw * 64);
#pragma unroll
        for (int q = 0; q < 8; ++q) {
            f32x4 v = xp[q];
            tv[q * 4 + 0] = tanhf(v[0]);
            tv[q * 4 + 1] = tanhf(v[1]);
            tv[q * 4 + 2] = tanhf(v[2]);
            tv[q * 4 + 3] = tanhf(v[3]);
        }

        // ---- recurrence state: (Vp,Vc) = (V_{d-2}, V_{d-1}) before d ----
        float Vp[32], Vc[32];
        int dlo, dhi;
        if (z == 0) {
            dlo = 0; dhi = (iw < 8) ? 4 : 3;
#pragma unroll
            for (int e = 0; e < 32; ++e) { Vp[e] = 2.0f; Vc[e] = tv[e]; }
        } else {
            dlo = (iw < 8) ? 5 : 4; dhi = 8;
#pragma unroll
            for (int e = 0; e < 32; ++e) {
                float V2 = tv[e] * tv[e] + 2.0f;
                float V3 = tv[e] * V2 + tv[e];
                if (iw >= 8) { Vp[e] = V2; Vc[e] = V3; }       // start d=4
                else { Vp[e] = V3; Vc[e] = tv[e] * V3 + V2; }  // start d=5
            }
        }

        for (int d = dlo; d <= dhi; ++d) {
            // ---- issue B DMA for this chunk ----
            const int koff = d * 1024 + iw * 64;
#pragma unroll
            for (int t = 0; t < 4; ++t) gl_lds16(gb[t] + koff, lb[t]);

            // ---- generate A-pane (overlaps B DMA) ----
            if (d == 0) {
                u32x4 w = (u32x4){0x40004000u, 0x40004000u, 0x40004000u, 0x40004000u};
#pragma unroll
                for (int cc = 0; cc < 4; ++cc) {
                    int pc = (ph * 4 + cc) ^ (pr & 7);
                    *(u32x4*)(ldsA + (pr * 8 + pc) * 8) = w;
                }
            } else if (d == 1) {
#pragma unroll
                for (int cc = 0; cc < 4; ++cc) {
                    int pc = (ph * 4 + cc) ^ (pr & 7);
                    u32x4 w;
#pragma unroll
                    for (int j = 0; j < 4; ++j)
                        w[j] = pack2bf(tv[cc * 8 + j * 2], tv[cc * 8 + j * 2 + 1]);
                    *(u32x4*)(ldsA + (pr * 8 + pc) * 8) = w;
                }
            } else {
#pragma unroll
                for (int e = 0; e < 32; ++e) {
                    float n = tv[e] * Vc[e] + Vp[e];
                    Vp[e] = Vc[e]; Vc[e] = n;
                }
#pragma unroll
                for (int cc = 0; cc < 4; ++cc) {
                    int pc = (ph * 4 + cc) ^ (pr & 7);
                    u32x4 w;
#pragma unroll
                    for (int j = 0; j < 4; ++j)
                        w[j] = pack2bf(Vc[cc * 8 + j * 2], Vc[cc * 8 + j * 2 + 1]);
                    *(u32x4*)(ldsA + (pr * 8 + pc) * 8) = w;
                }
            }
            __syncthreads();                      // drains DMA + ds_writes

            // ---- fragments + MFMA (identical to R4) ----
#pragma unroll
            for (int kk = 0; kk < 2; ++kk) {
                short8_t af[4], bfg[4];
#pragma unroll
                for (int mt = 0; mt < 4; ++mt) {
                    int row = wm * 64 + mt * 16 + l15;
                    int pc  = (kk * 4 + quad) ^ (row & 7);
                    af[mt] = *(const short8_t*)(ldsA + (row * 8 + pc) * 8);
                }
#pragma unroll
                for (int nt = 0; nt < 4; ++nt) {
                    int row = wn * 64 + nt * 16 + l15;
                    int pc  = (kk * 4 + quad) ^ (row & 7);
                    bfg[nt] = *(const short8_t*)(ldsB + (row * 8 + pc) * 8);
                }
#pragma unroll
                for (int mt = 0; mt < 4; ++mt)
#pragma unroll
                    for (int nt = 0; nt < 4; ++nt)
                        acc[mt][nt] = __builtin_amdgcn_mfma_f32_16x16x32_bf16(
                            af[mt], bfg[nt], acc[mt][nt], 0, 0, 0);
            }
            __syncthreads();
        }
    }

    // epilogue: C/D layout col = lane&15, row = quad*4 + reg  [m89-verified]
    float* C = P + (size_t)z * BATCH * ODIM;
#pragma unroll
    for (int mt = 0; mt < 4; ++mt) {
#pragma unroll
        for (int nt = 0; nt < 4; ++nt) {
            int row0 = bm * 128 + wm * 64 + mt * 16 + quad * 4;
            int col  = bn * 128 + wn * 64 + nt * 16 + l15;
#pragma unroll
            for (int r = 0; r < 4; ++r)
                C[(size_t)(row0 + r) * ODIM + col] = acc[mt][nt][r];
        }
    }
}

// out = P[0] + P[1]  (split-K reduction), float4 vectorized
__global__ void reduce_kernel(const float* __restrict__ P, float* __restrict__ out) {
    int t = blockIdx.x * 256 + threadIdx.x;
    f32x4 a = ((const f32x4*)P)[t];
    f32x4 b = ((const f32x4*)(P + (size_t)BATCH * ODIM))[t];
    ((f32x4*)out)[t] = a + b;
}

extern "C" void kernel_launch(void* const* d_in, const int* in_sizes, int n_in,
                              void* d_out, int out_size, void* d_ws, size_t ws_size,
                              hipStream_t stream) {
    const float* x      = (const float*)d_in[0];   // [4096,1024] f32
    const float* coeffs = (const float*)d_in[1];   // [1024,1024,9] f32
    float* out = (float*)d_out;                    // [4096,1024] f32

    u16* Bt = (u16*)d_ws;                          // 18.9 MB
    float* P = (float*)(Bt + (size_t)ODIM * KTOT); // 33.6 MB split-K partials

    prep_kernel<<<1024, 256, 0, stream>>>(coeffs, Bt);
    gemm_kernel<<<512, 256, 0, stream>>>(x, Bt, P);
    reduce_kernel<<<BATCH * ODIM / 1024, 256, 0, stream>>>(P, out);
}

// Round 8
// 190.729 us; speedup vs baseline: 1.6618x; 1.6618x over previous
//
#include <hip/hip_runtime.h>
#include <hip/hip_bf16.h>

typedef unsigned short u16;
typedef unsigned int   u32;
typedef unsigned long long u64;

#define BATCH 4096
#define IDIM  1024
#define ODIM  1024
#define NDEG  9                 // degree 8 -> 9 basis terms
#define KA    8192              // GEMM K: d=1..8 only (d=0 is rank-1, see below)
#define KAH   (KA / 2)          // 4096 per split-K half

typedef __attribute__((ext_vector_type(8))) short short8_t;   // 8 bf16 = 4 VGPRs
typedef __attribute__((ext_vector_type(4))) float f32x4;

// round-to-nearest-even f32 -> bf16
__device__ __forceinline__ u16 f2bf(float f) {
    union { float f; u32 u; } v; v.f = f;
    u32 r = v.u + 0x7FFFu + ((v.u >> 16) & 1u);
    return (u16)(r >> 16);
}
__device__ __forceinline__ u32 pack2bf(float lo, float hi) {
    return (u32)f2bf(lo) | ((u32)f2bf(hi) << 16);
}

// async 16B global -> LDS (wave-uniform LDS base + lane*16)
__device__ __forceinline__ void gl_lds16(const u16* g, u16* l) {
    __builtin_amdgcn_global_load_lds(
        (const __attribute__((address_space(1))) void*)g,
        (__attribute__((address_space(3))) void*)l,
        16, 0, 0);
}

// ---------------------------------------------------------------------------
// Fused prep (single dispatch, block-role split):
//   blocks [0, 1024)    : Bt[o][k=(d-1)*1024+i] <- coeffs[i][o][d], d=1..8
//                         + per-block partial sums of the d=0 column
//                         (rank-1 term: y += 2 * sum_i c[i,o,0], b-independent)
//   blocks [1024, 9216) : A[b][k=(d-1)*1024+i] <- V_d(tanh(x[b,i])), d=1..8
// ---------------------------------------------------------------------------
#define PB_TI 128
#define PB_TO 8
#define PB_J  (PB_TO * NDEG)    // 72
#define PB_LS 132               // LDS row stride (u16): 264 B, u64-aligned rows

#define NB_B   1024
#define NB_A   8192

__global__ void prep_kernel(const float* __restrict__ x,
                            const float* __restrict__ c,
                            u16* __restrict__ A, u16* __restrict__ Bt,
                            float* __restrict__ Pr) {
    __shared__ u16 lds[PB_J * PB_LS];             // 19 KB (B-blocks only)
    __shared__ float r1s[PB_TO];
    const int bb  = blockIdx.x;
    const int tid = threadIdx.x;

    if (bb < NB_B) {
        const int i0 = (bb & 7) * PB_TI;
        const int o0 = (bb >> 3) * PB_TO;
        const float* src = c + (size_t)i0 * (ODIM * NDEG) + (size_t)o0 * NDEG;
        if (tid < PB_TO) r1s[tid] = 0.0f;
        __syncthreads();
#pragma unroll
        for (int t = 0; t < 36; ++t) {            // 9216 floats / 256 threads
            int f  = t * 256 + tid;
            int ii = f / PB_J;
            int j  = f - ii * PB_J;
            float v = src[(size_t)ii * (ODIM * NDEG) + j];
            lds[j * PB_LS + ii] = f2bf(v);
            int o = j / NDEG;
            int d = j - o * NDEG;
            if (d == 0) atomicAdd(&r1s[o], v);    // f32 column-sum (exact path)
        }
        __syncthreads();
#pragma unroll
        for (int t = 0; t < 9; ++t) {             // 72*32 u64 groups / 256 thr
            int g   = t * 256 + tid;
            int j   = g >> 5;                     // 0..71
            int ii4 = (g & 31) << 2;
            int o   = j / NDEG;
            int d   = j - o * NDEG;
            if (d != 0) {
                u64 v = *(const u64*)(lds + j * PB_LS + ii4);
                *(u64*)(Bt + (size_t)(o0 + o) * KA + (d - 1) * 1024 + i0 + ii4) = v;
            }
        }
        if (tid < PB_TO)                          // deterministic partials
            Pr[(size_t)(bb & 7) * ODIM + o0 + tid] = r1s[tid];
    } else {
        // ---- A basis (planes d=1..8): thread handles 2 consecutive i ----
        int t  = (bb - NB_B) * 256 + tid;
        int b  = t >> 9;
        int i2 = (t & 511) << 1;
        float2 xv = ((const float2*)x)[t];
        float t0 = tanhf(xv.x), t1 = tanhf(xv.y);
        u32* dst = (u32*)(A + (size_t)b * KA + i2);  // plane stride 512 u32
        float a0 = 2.0f, a1 = 2.0f;
        float b0 = t0,  b1 = t1;
        dst[0] = pack2bf(t0, t1);                 // d=1 at plane 0
#pragma unroll
        for (int d = 2; d < NDEG; ++d) {
            float n0 = t0 * b0 + a0;
            float n1 = t1 * b1 + a1;
            dst[(size_t)(d - 1) * 512] = pack2bf(n0, n1);
            a0 = b0; b0 = n0; a1 = b1; b1 = n1;
        }
    }
}

// ---------------------------------------------------------------------------
// GEMM: P[z][m][n] = A[m][k] * Bt[n][k] over K half (d=1..4 | d=5..8),
// 128x128 tile, BK=64, 4 waves of 64x64 — R4-verified structure (920 TF).
// XCD swizzle (id%8 -> XCD): each XCD owns a 1024x1024 output patch at
// half-K -> FETCH measured 73.8 MB at K=9216 (A streams once, B from LLC).
// LDS: [row][8 chunks of 16B], physical chunk = c ^ (row&7)
// -> global_load_lds staging + conflict-free ds_read_b128 (0 conflicts).
// ---------------------------------------------------------------------------
__global__ __launch_bounds__(256, 2)
void gemm_kernel(const u16* __restrict__ A, const u16* __restrict__ B,
                 float* __restrict__ P) {
    __shared__ __align__(16) u16 ldsA[128 * 64];  // 16 KB
    __shared__ __align__(16) u16 ldsB[128 * 64];  // 16 KB

    const int tid  = threadIdx.x;
    const int lane = tid & 63;
    const int wave = tid >> 6;
    const int quad = lane >> 4;
    const int l15  = lane & 15;
    const int wm   = wave & 1;
    const int wn   = wave >> 1;

    const int bid = blockIdx.x;                   // 0..511
    const int xcd = bid & 7;
    const int loc = bid >> 3;                     // 0..63
    const int z   = xcd >> 2;
    const int bm  = ((xcd & 3) << 3) | (loc >> 3);
    const int bn  = loc & 7;
    const int kStart = z * KAH;

    const u16* ga[4]; const u16* gb[4];
    u16* la[4]; u16* lb[4];
#pragma unroll
    for (int t = 0; t < 4; ++t) {
        int s  = t * 256 + tid;                   // 16B slot in tile, 0..1023
        int r  = s >> 3;                          // tile row 0..127
        int sc = (s & 7) ^ (r & 7);               // source k-chunk (XOR swizzle)
        ga[t] = A + (size_t)(bm * 128 + r) * KA + kStart + sc * 8;
        gb[t] = B + (size_t)(bn * 128 + r) * KA + kStart + sc * 8;
        la[t] = ldsA + s * 8;
        lb[t] = ldsB + s * 8;
    }

    f32x4 acc[4][4];
#pragma unroll
    for (int mt = 0; mt < 4; ++mt)
#pragma unroll
        for (int nt = 0; nt < 4; ++nt)
            acc[mt][nt] = (f32x4){0.f, 0.f, 0.f, 0.f};

    const int nIter = KAH / 64;                   // 64
    for (int it = 0; it < nIter; ++it) {
#pragma unroll
        for (int t = 0; t < 4; ++t) gl_lds16(ga[t], la[t]);
#pragma unroll
        for (int t = 0; t < 4; ++t) gl_lds16(gb[t], lb[t]);
        __syncthreads();

#pragma unroll
        for (int kk = 0; kk < 2; ++kk) {
            short8_t af[4], bfg[4];
#pragma unroll
            for (int mt = 0; mt < 4; ++mt) {
                int row = wm * 64 + mt * 16 + l15;
                int pc  = (kk * 4 + quad) ^ (row & 7);
                af[mt] = *(const short8_t*)(ldsA + (row * 8 + pc) * 8);
            }
#pragma unroll
            for (int nt = 0; nt < 4; ++nt) {
                int row = wn * 64 + nt * 16 + l15;
                int pc  = (kk * 4 + quad) ^ (row & 7);
                bfg[nt] = *(const short8_t*)(ldsB + (row * 8 + pc) * 8);
            }
#pragma unroll
            for (int mt = 0; mt < 4; ++mt)
#pragma unroll
                for (int nt = 0; nt < 4; ++nt)
                    acc[mt][nt] = __builtin_amdgcn_mfma_f32_16x16x32_bf16(
                        af[mt], bfg[nt], acc[mt][nt], 0, 0, 0);
        }
        __syncthreads();

#pragma unroll
        for (int t = 0; t < 4; ++t) { ga[t] += 64; gb[t] += 64; }
    }

    // epilogue: C/D layout col = lane&15, row = quad*4 + reg  [m89-verified]
    float* C = P + (size_t)z * BATCH * ODIM;
#pragma unroll
    for (int mt = 0; mt < 4; ++mt) {
#pragma unroll
        for (int nt = 0; nt < 4; ++nt) {
            int row0 = bm * 128 + wm * 64 + mt * 16 + quad * 4;
            int col  = bn * 128 + wn * 64 + nt * 16 + l15;
#pragma unroll
            for (int r = 0; r < 4; ++r)
                C[(size_t)(row0 + r) * ODIM + col] = acc[mt][nt][r];
        }
    }
}

// out = P[0] + P[1] + 2 * sum_blk Pr[blk][o]   (split-K + rank-1 d=0 term)
__global__ void reduce_kernel(const float* __restrict__ P,
                              const float* __restrict__ Pr,
                              float* __restrict__ out) {
    int t  = blockIdx.x * 256 + threadIdx.x;      // over BATCH*ODIM/4
    int o4 = t & 255;                             // f32x4 column index
    f32x4 a = ((const f32x4*)P)[t];
    a += ((const f32x4*)(P + (size_t)BATCH * ODIM))[t];
    f32x4 r = (f32x4){0.f, 0.f, 0.f, 0.f};
#pragma unroll
    for (int blk = 0; blk < 8; ++blk)
        r += ((const f32x4*)Pr)[blk * 256 + o4];  // hot in L2 (32 KB table)
    ((f32x4*)out)[t] = a + r + r;                 // + 2*r  (V0 = 2)
}

extern "C" void kernel_launch(void* const* d_in, const int* in_sizes, int n_in,
                              void* d_out, int out_size, void* d_ws, size_t ws_size,
                              hipStream_t stream) {
    const float* x      = (const float*)d_in[0];   // [4096,1024] f32
    const float* coeffs = (const float*)d_in[1];   // [1024,1024,9] f32
    float* out = (float*)d_out;                    // [4096,1024] f32

    u16*   A  = (u16*)d_ws;                        // 67.1 MB
    u16*   Bt = A + (size_t)BATCH * KA;            // 16.8 MB
    float* Pr = (float*)(Bt + (size_t)ODIM * KA);  // 32 KB rank-1 partials
    float* P  = Pr + 8 * ODIM;                     // 33.6 MB split-K partials

    prep_kernel<<<NB_B + NB_A, 256, 0, stream>>>(x, coeffs, A, Bt, Pr);
    gemm_kernel<<<512, 256, 0, stream>>>(A, Bt, P);
    reduce_kernel<<<BATCH * ODIM / 1024, 256, 0, stream>>>(P, Pr, out);
}

// Round 9
// 177.709 us; speedup vs baseline: 1.7836x; 1.0733x over previous
//
#include <hip/hip_runtime.h>
#include <hip/hip_bf16.h>

typedef unsigned short u16;
typedef unsigned int   u32;
typedef unsigned long long u64;

#define BATCH 4096
#define IDIM  1024
#define ODIM  1024
#define NDEG  9                 // degree 8 -> 9 basis terms
#define KA    8192              // GEMM K: d=1..8 only (d=0 is rank-1, see below)
#define KAH   (KA / 2)          // 4096 per split-K half

typedef __attribute__((ext_vector_type(8))) short short8_t;   // 8 bf16 = 4 VGPRs
typedef __attribute__((ext_vector_type(4))) float f32x4;

// round-to-nearest-even f32 -> bf16
__device__ __forceinline__ u16 f2bf(float f) {
    union { float f; u32 u; } v; v.f = f;
    u32 r = v.u + 0x7FFFu + ((v.u >> 16) & 1u);
    return (u16)(r >> 16);
}
__device__ __forceinline__ u32 pack2bf(float lo, float hi) {
    return (u32)f2bf(lo) | ((u32)f2bf(hi) << 16);
}
__device__ __forceinline__ float bf2f(u16 h) {
    union { u32 u; float f; } v; v.u = (u32)h << 16; return v.f;
}

// async 16B global -> LDS (wave-uniform LDS base + lane*16)
__device__ __forceinline__ void gl_lds16(const u16* g, u16* l) {
    __builtin_amdgcn_global_load_lds(
        (const __attribute__((address_space(1))) void*)g,
        (__attribute__((address_space(3))) void*)l,
        16, 0, 0);
}

// ---------------------------------------------------------------------------
// Fused prep (single dispatch, block-role split):
//   blocks [0, 1024)    : Bt[o][k=(d-1)*1024+i] <- coeffs[i][o][d], d=1..8
//                         + rank-1 partials sum_i c[i,o,0] (atomic-FREE:
//                         bf16 LDS re-read + wave shuffle; R8's LDS atomicAdd
//                         serialized ~1024 ops/block -> ~12 us prep regression)
//   blocks [1024, 9216) : A[b][k=(d-1)*1024+i] <- V_d(tanh(x[b,i])), d=1..8
// ---------------------------------------------------------------------------
#define PB_TI 128
#define PB_TO 8
#define PB_J  (PB_TO * NDEG)    // 72
#define PB_LS 132               // LDS row stride (u16): 264 B, u64-aligned rows

#define NB_B   1024
#define NB_A   8192

__global__ void prep_kernel(const float* __restrict__ x,
                            const float* __restrict__ c,
                            u16* __restrict__ A, u16* __restrict__ Bt,
                            float* __restrict__ Pr) {
    __shared__ u16 lds[PB_J * PB_LS];             // 19 KB (B-blocks only)
    const int bb  = blockIdx.x;
    const int tid = threadIdx.x;

    if (bb < NB_B) {
        const int i0 = (bb & 7) * PB_TI;
        const int o0 = (bb >> 3) * PB_TO;
        const float* src = c + (size_t)i0 * (ODIM * NDEG) + (size_t)o0 * NDEG;
#pragma unroll
        for (int t = 0; t < 36; ++t) {            // 9216 floats / 256 threads
            int f  = t * 256 + tid;
            int ii = f / PB_J;
            int j  = f - ii * PB_J;
            float v = src[(size_t)ii * (ODIM * NDEG) + j];
            lds[j * PB_LS + ii] = f2bf(v);
        }
        __syncthreads();

        // ---- rank-1 column sums from the d=0 LDS row (bf16 -> f32 exact
        // accumulation; bf16 rounding adds ~4e-6 rms, negligible) ----
        {
            int o   = tid >> 5;                   // 0..7
            int sub = tid & 31;                   // 32 threads per o
            const u16* row = lds + (o * NDEG) * PB_LS + sub * 4;
            float s = bf2f(row[0]) + bf2f(row[1]) + bf2f(row[2]) + bf2f(row[3]);
#pragma unroll
            for (int m = 16; m >= 1; m >>= 1)     // stays within 32-lane halves
                s += __shfl_xor(s, m, 64);
            if (sub == 0)                         // deterministic partials
                Pr[(size_t)(bb & 7) * ODIM + o0 + o] = s;
        }

#pragma unroll
        for (int t = 0; t < 9; ++t) {             // 72*32 u64 groups / 256 thr
            int g   = t * 256 + tid;
            int j   = g >> 5;                     // 0..71
            int ii4 = (g & 31) << 2;
            int o   = j / NDEG;
            int d   = j - o * NDEG;
            if (d != 0) {
                u64 v = *(const u64*)(lds + j * PB_LS + ii4);
                *(u64*)(Bt + (size_t)(o0 + o) * KA + (d - 1) * 1024 + i0 + ii4) = v;
            }
        }
    } else {
        // ---- A basis (planes d=1..8): thread handles 2 consecutive i ----
        int t  = (bb - NB_B) * 256 + tid;
        int b  = t >> 9;
        int i2 = (t & 511) << 1;
        float2 xv = ((const float2*)x)[t];
        float t0 = tanhf(xv.x), t1 = tanhf(xv.y);
        u32* dst = (u32*)(A + (size_t)b * KA + i2);  // plane stride 512 u32
        float a0 = 2.0f, a1 = 2.0f;
        float b0 = t0,  b1 = t1;
        dst[0] = pack2bf(t0, t1);                 // d=1 at plane 0
#pragma unroll
        for (int d = 2; d < NDEG; ++d) {
            float n0 = t0 * b0 + a0;
            float n1 = t1 * b1 + a1;
            dst[(size_t)(d - 1) * 512] = pack2bf(n0, n1);
            a0 = b0; b0 = n0; a1 = b1; b1 = n1;
        }
    }
}

// ---------------------------------------------------------------------------
// GEMM: P[z][m][n] = A[m][k] * Bt[n][k] over K half (d=1..4 | d=5..8),
// 128x128 tile, BK=64, 4 waves of 64x64 — R4-verified structure (917 TF).
// XCD swizzle (id%8 -> XCD): each XCD owns a 1024x1024 output patch at
// half-K -> FETCH at the compulsory floor (65.6 MB measured).
// LDS: [row][8 chunks of 16B], physical chunk = c ^ (row&7)
// -> global_load_lds staging + conflict-free ds_read_b128 (0 conflicts).
// ---------------------------------------------------------------------------
__global__ __launch_bounds__(256, 2)
void gemm_kernel(const u16* __restrict__ A, const u16* __restrict__ B,
                 float* __restrict__ P) {
    __shared__ __align__(16) u16 ldsA[128 * 64];  // 16 KB
    __shared__ __align__(16) u16 ldsB[128 * 64];  // 16 KB

    const int tid  = threadIdx.x;
    const int lane = tid & 63;
    const int wave = tid >> 6;
    const int quad = lane >> 4;
    const int l15  = lane & 15;
    const int wm   = wave & 1;
    const int wn   = wave >> 1;

    const int bid = blockIdx.x;                   // 0..511
    const int xcd = bid & 7;
    const int loc = bid >> 3;                     // 0..63
    const int z   = xcd >> 2;
    const int bm  = ((xcd & 3) << 3) | (loc >> 3);
    const int bn  = loc & 7;
    const int kStart = z * KAH;

    const u16* ga[4]; const u16* gb[4];
    u16* la[4]; u16* lb[4];
#pragma unroll
    for (int t = 0; t < 4; ++t) {
        int s  = t * 256 + tid;                   // 16B slot in tile, 0..1023
        int r  = s >> 3;                          // tile row 0..127
        int sc = (s & 7) ^ (r & 7);               // source k-chunk (XOR swizzle)
        ga[t] = A + (size_t)(bm * 128 + r) * KA + kStart + sc * 8;
        gb[t] = B + (size_t)(bn * 128 + r) * KA + kStart + sc * 8;
        la[t] = ldsA + s * 8;
        lb[t] = ldsB + s * 8;
    }

    f32x4 acc[4][4];
#pragma unroll
    for (int mt = 0; mt < 4; ++mt)
#pragma unroll
        for (int nt = 0; nt < 4; ++nt)
            acc[mt][nt] = (f32x4){0.f, 0.f, 0.f, 0.f};

    const int nIter = KAH / 64;                   // 64
    for (int it = 0; it < nIter; ++it) {
#pragma unroll
        for (int t = 0; t < 4; ++t) gl_lds16(ga[t], la[t]);
#pragma unroll
        for (int t = 0; t < 4; ++t) gl_lds16(gb[t], lb[t]);
        __syncthreads();

#pragma unroll
        for (int kk = 0; kk < 2; ++kk) {
            short8_t af[4], bfg[4];
#pragma unroll
            for (int mt = 0; mt < 4; ++mt) {
                int row = wm * 64 + mt * 16 + l15;
                int pc  = (kk * 4 + quad) ^ (row & 7);
                af[mt] = *(const short8_t*)(ldsA + (row * 8 + pc) * 8);
            }
#pragma unroll
            for (int nt = 0; nt < 4; ++nt) {
                int row = wn * 64 + nt * 16 + l15;
                int pc  = (kk * 4 + quad) ^ (row & 7);
                bfg[nt] = *(const short8_t*)(ldsB + (row * 8 + pc) * 8);
            }
#pragma unroll
            for (int mt = 0; mt < 4; ++mt)
#pragma unroll
                for (int nt = 0; nt < 4; ++nt)
                    acc[mt][nt] = __builtin_amdgcn_mfma_f32_16x16x32_bf16(
                        af[mt], bfg[nt], acc[mt][nt], 0, 0, 0);
        }
        __syncthreads();

#pragma unroll
        for (int t = 0; t < 4; ++t) { ga[t] += 64; gb[t] += 64; }
    }

    // epilogue: C/D layout col = lane&15, row = quad*4 + reg  [m89-verified]
    float* C = P + (size_t)z * BATCH * ODIM;
#pragma unroll
    for (int mt = 0; mt < 4; ++mt) {
#pragma unroll
        for (int nt = 0; nt < 4; ++nt) {
            int row0 = bm * 128 + wm * 64 + mt * 16 + quad * 4;
            int col  = bn * 128 + wn * 64 + nt * 16 + l15;
#pragma unroll
            for (int r = 0; r < 4; ++r)
                C[(size_t)(row0 + r) * ODIM + col] = acc[mt][nt][r];
        }
    }
}

// out = P[0] + P[1] + 2 * sum_blk Pr[blk][o]   (split-K + rank-1 d=0 term)
__global__ void reduce_kernel(const float* __restrict__ P,
                              const float* __restrict__ Pr,
                              float* __restrict__ out) {
    int t  = blockIdx.x * 256 + threadIdx.x;      // over BATCH*ODIM/4
    int o4 = t & 255;                             // f32x4 column index
    f32x4 a = ((const f32x4*)P)[t];
    a += ((const f32x4*)(P + (size_t)BATCH * ODIM))[t];
    f32x4 r = (f32x4){0.f, 0.f, 0.f, 0.f};
#pragma unroll
    for (int blk = 0; blk < 8; ++blk)
        r += ((const f32x4*)Pr)[blk * 256 + o4];  // hot in L2 (32 KB table)
    ((f32x4*)out)[t] = a + r + r;                 // + 2*r  (V0 = 2)
}

extern "C" void kernel_launch(void* const* d_in, const int* in_sizes, int n_in,
                              void* d_out, int out_size, void* d_ws, size_t ws_size,
                              hipStream_t stream) {
    const float* x      = (const float*)d_in[0];   // [4096,1024] f32
    const float* coeffs = (const float*)d_in[1];   // [1024,1024,9] f32
    float* out = (float*)d_out;                    // [4096,1024] f32

    u16*   A  = (u16*)d_ws;                        // 67.1 MB
    u16*   Bt = A + (size_t)BATCH * KA;            // 16.8 MB
    float* Pr = (float*)(Bt + (size_t)ODIM * KA);  // 32 KB rank-1 partials
    float* P  = Pr + 8 * ODIM;                     // 33.6 MB split-K partials

    prep_kernel<<<NB_B + NB_A, 256, 0, stream>>>(x, coeffs, A, Bt, Pr);
    gemm_kernel<<<512, 256, 0, stream>>>(A, Bt, P);
    reduce_kernel<<<BATCH * ODIM / 1024, 256, 0, stream>>>(P, Pr, out);
}